// Round 11
// baseline (221.049 us; speedup 1.0000x reference)
//
#include <hip/hip_runtime.h>

#define IN_F 4096
#define OUT_F 11008
#define NCLUST 16
#define TOPK 1024
#define NW 16
#define ROWS_PB 43          // 256 blocks * 43 rows = 11008
#define HALF_F 2048         // half row (floats) DMA'd per wave
#define MAGIC 0x5D3A7F21u

typedef float f4 __attribute__((ext_vector_type(4)));

__device__ __forceinline__ float dotf4(f4 a, f4 b) {
    return a[0] * b[0] + a[1] * b[1] + a[2] * b[2] + a[3] * b[3];
}
__device__ __forceinline__ float wredsum(float v) {
    for (int o = 32; o > 0; o >>= 1) v += __shfl_down(v, o, 64);
    return v;
}

// ws layout (floats): [0..4095]=xm, [4096]=flag, [4097]=done,
//                     [4104..4119]=slot_dot, [4120..4135]=slot_csq
__global__ __launch_bounds__(1024) void fused_kernel(
    const float* __restrict__ x,
    const float* __restrict__ W,
    const float* __restrict__ bias,
    const float* __restrict__ centers,
    float* __restrict__ out,
    float* __restrict__ ws)
{
    const int tid  = threadIdx.x;
    const int lane = tid & 63;
    const int wid  = tid >> 6;
    const int bid  = blockIdx.x;
    const int rbase = bid * ROWS_PB;

    __shared__ __align__(16) float wstage[NW][HALF_F];  // 128 KB DMA dest
    __shared__ __align__(16) float sxm[IN_F];           // 16 KB: hist then xm
    __shared__ float swred[NW], sdt[NW], scq[NW];
    __shared__ unsigned int wtot4[4], weq[NW];
    __shared__ unsigned int sprefix, sKrem, sG;
    __shared__ int sci, sfin;

    unsigned int* hist = (unsigned int*)sxm;            // alias (pre-xm only)
    unsigned int* flag = (unsigned int*)(ws + IN_F);
    unsigned int* done = (unsigned int*)(ws + IN_F + 1);
    float* slot_dot = ws + IN_F + 8;
    float* slot_csq = ws + IN_F + 24;
    f4* sxm4 = (f4*)sxm;

    // ---- 1. DMA prologue: first 8 KB of row (rbase+wid) into LDS ----
    {
        const int row0 = rbase + wid;
        const float* src = W + (size_t)row0 * IN_F + lane * 4;
        float* dst = &wstage[wid][0];
        #pragma unroll
        for (int j = 0; j < 8; ++j) {
            __builtin_amdgcn_global_load_lds(
                (const __attribute__((address_space(1))) void*)(src + j * 256),
                (__attribute__((address_space(3))) void*)(dst + j * 256),
                16, 0, 0);
        }
    }

    // ---- 2. distributed select: blocks 0..15, one cluster each ----
    if (bid < NCLUST) {
        f4 xv = ((const f4*)x)[tid];
        f4 ev;
        ev[0] = expf(fabsf(xv[0])); ev[1] = expf(fabsf(xv[1]));
        ev[2] = expf(fabsf(xv[2])); ev[3] = expf(fabsf(xv[3]));
        {
            float s = wredsum(ev[0] + ev[1] + ev[2] + ev[3]);
            if (lane == 0) swred[wid] = s;
        }
        // this block's cluster partials
        f4 cvv = ((const f4*)(centers + (size_t)bid * IN_F))[tid];
        {
            float dt = wredsum(dotf4(cvv, ev));
            float cq = wredsum(dotf4(cvv, cvv));
            if (lane == 0) { sdt[wid] = dt; scq[wid] = cq; }
        }
        __syncthreads();
        float S = 0.0f, dotb = 0.0f, csqb = 0.0f;
        #pragma unroll
        for (int k = 0; k < NW; ++k) { S += swred[k]; dotb += sdt[k]; csqb += scq[k]; }
        if (tid == 0) {
            slot_dot[bid] = dotb;
            slot_csq[bid] = csqb;
            __threadfence();
            unsigned int old = __hip_atomic_fetch_add(done, 1u, __ATOMIC_ACQ_REL,
                                                      __HIP_MEMORY_SCOPE_AGENT);
            sfin = (old == NCLUST - 1) ? 1 : 0;
        }
        __syncthreads();

        if (sfin) {
            // ---- finalizer: argmin + radix + mask + publish ----
            __threadfence();
            if (wid == 0) {
                float v = 3.0e38f;
                int bi = lane;
                if (lane < NCLUST)
                    v = slot_csq[lane] - (2.0f / S) * slot_dot[lane];
                for (int off = 8; off > 0; off >>= 1) {
                    float ov = __shfl_down(v, off, 64);
                    int   oi = __shfl_down(bi, off, 64);
                    if (ov < v) { v = ov; bi = oi; }   // strict <: first index
                }
                if (lane == 0) sci = bi;
            }
            if (tid == 0) { sprefix = 0u; sKrem = TOPK; sG = 0u; }
            // clear hist (aliases sxm)
            hist[tid] = 0u; hist[tid + 1024] = 0u;
            hist[tid + 2048] = 0u; hist[tid + 3072] = 0u;
            __syncthreads();

            // chosen center (positive floats: uint cmp == float cmp)
            unsigned int cv[4];
            {
                f4 c = ((const f4*)(centers + (size_t)sci * IN_F))[tid];
                cv[0] = __float_as_uint(c[0]); cv[1] = __float_as_uint(c[1]);
                cv[2] = __float_as_uint(c[2]); cv[3] = __float_as_uint(c[3]);
            }

            // 4-pass radix select for the 1024th-largest value
            for (int pass = 0; pass < 4; ++pass) {
                const int shift = 24 - 8 * pass;
                const unsigned int pfx  = sprefix;
                const unsigned int krem = sKrem;
                unsigned int* hp = &hist[wid * 256];
                #pragma unroll
                for (int j = 0; j < 4; ++j) {
                    unsigned int u = cv[j];
                    bool cand = (pass == 0) || ((u >> (shift + 8)) == pfx);
                    if (cand) atomicAdd(&hp[(u >> shift) & 255u], 1u);
                }
                __syncthreads();
                unsigned int h = 0, s = 0;
                if (tid < 256) {
                    #pragma unroll
                    for (int w = 0; w < NW; ++w) { h += hist[w * 256 + tid]; hist[w * 256 + tid] = 0u; }
                    s = h;  // suffix-inclusive scan within wave (bin order)
                    for (int off = 1; off < 64; off <<= 1) {
                        unsigned int v2 = __shfl_down(s, off, 64);
                        if (lane + off < 64) s += v2;
                    }
                    if (lane == 0) wtot4[wid] = s;
                }
                __syncthreads();
                if (tid < 256) {
                    unsigned int add = 0;
                    #pragma unroll
                    for (int w2 = 0; w2 < 4; ++w2) if (w2 > wid) add += wtot4[w2];
                    unsigned int incl = s + add;
                    unsigned int excl = incl - h;
                    if (excl < krem && krem <= incl) {
                        sprefix = (pfx << 8) | (unsigned int)tid;
                        sKrem   = krem - excl;
                    }
                }
                __syncthreads();
            }
            const unsigned int T = sprefix;

            // tie bookkeeping (stable: first (TOPK-G) equals in index order)
            unsigned int gt = 0, eq = 0;
            #pragma unroll
            for (int j = 0; j < 4; ++j) {
                gt += (cv[j] > T) ? 1u : 0u;
                eq += (cv[j] == T) ? 1u : 0u;
            }
            {
                unsigned int g = gt;
                for (int o = 32; o > 0; o >>= 1) g += __shfl_down(g, o, 64);
                if (lane == 0) atomicAdd(&sG, g);
            }
            unsigned int p = eq;
            for (int off = 1; off < 64; off <<= 1) {
                unsigned int v2 = __shfl_up(p, off, 64);
                if (lane >= off) p += v2;
            }
            if (lane == 63) weq[wid] = p;
            __syncthreads();
            unsigned int base = p - eq;
            #pragma unroll
            for (int w = 0; w < NW; ++w) if (w < wid) base += weq[w];
            const unsigned int needEq = TOPK - sG;

            // emit masked x to global xm, then release flag
            {
                unsigned int r = 0;
                f4 o;
                o[0] = ((cv[0] > T) || ((cv[0] == T) && (base + r < needEq))) ? xv[0] : 0.0f; r += (cv[0] == T);
                o[1] = ((cv[1] > T) || ((cv[1] == T) && (base + r < needEq))) ? xv[1] : 0.0f; r += (cv[1] == T);
                o[2] = ((cv[2] > T) || ((cv[2] == T) && (base + r < needEq))) ? xv[2] : 0.0f; r += (cv[2] == T);
                o[3] = ((cv[3] > T) || ((cv[3] == T) && (base + r < needEq))) ? xv[3] : 0.0f;
                ((f4*)ws)[tid] = o;
            }
            __threadfence();
            __syncthreads();
            if (tid == 0)
                __hip_atomic_store(flag, MAGIC, __ATOMIC_RELEASE,
                                   __HIP_MEMORY_SCOPE_AGENT);
        }
    }

    // ---- 3. wait for mask (DMA stays in flight; finalizer passes through) ----
    if (tid == 0) {
        while (__hip_atomic_load(flag, __ATOMIC_ACQUIRE,
                                 __HIP_MEMORY_SCOPE_AGENT) != MAGIC)
            __builtin_amdgcn_s_sleep(8);
    }
    __syncthreads();
    __threadfence();

    // ---- 4. stage xm into LDS (overwrites hist alias; finalizer is done) ----
    sxm4[tid] = ((const f4*)ws)[tid];
    __syncthreads();   // drains vmcnt(0): DMA half-rows + xm loads all landed

    // ---- 5. row 0: first half from LDS DMA, second half from global ----
    {
        const int row0 = rbase + wid;
        const f4* wb = (const f4*)&wstage[wid][0];
        const f4* wr = (const f4*)(W + (size_t)row0 * IN_F);
        float acc = 0.0f;
        #pragma unroll
        for (int j = 0; j < 8; ++j)
            acc += dotf4(wb[j * 64 + lane], sxm4[j * 64 + lane]);
        #pragma unroll
        for (int j = 8; j < 16; ++j)
            acc += dotf4(wr[j * 64 + lane], sxm4[j * 64 + lane]);
        acc = wredsum(acc);
        if (lane == 0) out[row0] = acc + bias[row0];
    }

    // ---- 6. remaining rows: plain streaming (R8 engine, LDS xm) ----
    for (int r = wid + NW; r < ROWS_PB; r += NW) {
        const int row = rbase + r;
        const f4* wr = (const f4*)(W + (size_t)row * IN_F);
        float acc = 0.0f;
        #pragma unroll
        for (int j = 0; j < 16; ++j)
            acc += dotf4(wr[j * 64 + lane], sxm4[j * 64 + lane]);
        acc = wredsum(acc);
        if (lane == 0) out[row] = acc + bias[row];
    }
}

extern "C" void kernel_launch(void* const* d_in, const int* in_sizes, int n_in,
                              void* d_out, int out_size, void* d_ws, size_t ws_size,
                              hipStream_t stream) {
    const float* x       = (const float*)d_in[0];  // [1,1,4096]
    const float* weight  = (const float*)d_in[1];  // [11008,4096]
    const float* bias    = (const float*)d_in[2];  // [11008]
    const float* centers = (const float*)d_in[3];  // [16,4096]
    float* out = (float*)d_out;                    // [11008]
    float* ws  = (float*)d_ws;                     // xm[4096] + flag/done/slots

    // reset flag + done (8 bytes) every launch — graph-capturable async memset
    hipMemsetAsync((void*)(ws + IN_F), 0, 8, stream);
    fused_kernel<<<256, 1024, 0, stream>>>(x, weight, bias, centers, out, ws);
}

// Round 12
// 43.359 us; speedup vs baseline: 5.0981x; 5.0981x over previous
//
#include <hip/hip_runtime.h>

#define IN_F 4096
#define OUT_F 11008
#define NCLUST 16
#define TOPK 1024
#define NT 1024
#define NW 16
#define ROWS_PB 43      // 256 blocks * 43 rows = 11008

typedef float f4 __attribute__((ext_vector_type(4)));

__device__ __forceinline__ float dotf4(f4 a, f4 b) {
    return a[0] * b[0] + a[1] * b[1] + a[2] * b[2] + a[3] * b[3];
}
__device__ __forceinline__ float wredsum(float v) {
    for (int o = 32; o > 0; o >>= 1) v += __shfl_down(v, o, 64);
    return v;
}

// ---------------------------------------------------------------------------
// Kernel A: select mask (1 block, 1024 threads, 16 waves). R8-proven.
// ---------------------------------------------------------------------------
__global__ __launch_bounds__(NT) void select_mask_kernel(
    const float* __restrict__ x,
    const float* __restrict__ centers,
    float* __restrict__ xm)
{
    const int tid  = threadIdx.x;
    const int lane = tid & 63;
    const int wid  = tid >> 6;

    __shared__ __align__(16) float sact[IN_F];   // e values
    __shared__ unsigned int hist[NW * 256];      // per-wave private histograms
    __shared__ float swred[NW];
    __shared__ float sdot[NCLUST], scsq[NCLUST];
    __shared__ unsigned int wtot4[4], weq[NW];
    __shared__ unsigned int sprefix, sKrem, sG;
    __shared__ int sci;

    if (tid == 0) { sprefix = 0u; sKrem = TOPK; sG = 0u; }

    // ---- x load + e = exp(|x|) -> LDS + wave sums; clear histograms ----
    float4 xv = reinterpret_cast<const float4*>(x)[tid];
    float e0 = expf(fabsf(xv.x)), e1 = expf(fabsf(xv.y));
    float e2 = expf(fabsf(xv.z)), e3 = expf(fabsf(xv.w));
    reinterpret_cast<float4*>(sact)[tid] = make_float4(e0, e1, e2, e3);
    {
        float s = wredsum(e0 + e1 + e2 + e3);
        if (lane == 0) swred[wid] = s;
        hist[tid] = 0u; hist[tid + 1024] = 0u;
        hist[tid + 2048] = 0u; hist[tid + 3072] = 0u;
    }
    __syncthreads();
    float S = 0.0f;
    #pragma unroll
    for (int k = 0; k < NW; ++k) S += swred[k];   // LDS broadcast reads

    // ---- per-cluster dot(c,e), sum(c^2): wave w -> cluster w ----
    {
        const float4* cp = reinterpret_cast<const float4*>(centers + (size_t)wid * IN_F);
        const float4* a4 = reinterpret_cast<const float4*>(sact);
        float dt = 0.0f, cq = 0.0f;
        #pragma unroll
        for (int j = 0; j < 16; ++j) {
            float4 c = cp[j * 64 + lane];
            float4 a = a4[j * 64 + lane];
            dt += c.x * a.x + c.y * a.y + c.z * a.z + c.w * a.w;
            cq += c.x * c.x + c.y * c.y + c.z * c.z + c.w * c.w;
        }
        dt = wredsum(dt);
        cq = wredsum(cq);
        if (lane == 0) { sdot[wid] = dt; scsq[wid] = cq; }
    }
    __syncthreads();

    // ---- argmin_cl [ sum(c^2) - (2/S) dot(c,e) ]  (strict <: first index) ----
    if (wid == 0) {
        float v = (lane < NCLUST) ? (scsq[lane] - (2.0f / S) * sdot[lane]) : 3.0e38f;
        int bi = lane;
        for (int off = 8; off > 0; off >>= 1) {
            float ov = __shfl_down(v, off, 64);
            int   oi = __shfl_down(bi, off, 64);
            if (ov < v) { v = ov; bi = oi; }
        }
        if (lane == 0) sci = bi;
    }
    __syncthreads();

    // ---- chosen center (positive floats: uint cmp == float cmp) ----
    unsigned int cv[4];
    {
        float4 c = reinterpret_cast<const float4*>(centers + (size_t)sci * IN_F)[tid];
        cv[0] = __float_as_uint(c.x); cv[1] = __float_as_uint(c.y);
        cv[2] = __float_as_uint(c.z); cv[3] = __float_as_uint(c.w);
    }

    // ---- 4-pass radix select for the 1024th-largest value ----
    for (int pass = 0; pass < 4; ++pass) {
        const int shift = 24 - 8 * pass;
        const unsigned int pfx  = sprefix;
        const unsigned int krem = sKrem;
        unsigned int* hp = &hist[wid * 256];
        #pragma unroll
        for (int j = 0; j < 4; ++j) {
            unsigned int u = cv[j];
            bool cand = (pass == 0) || ((u >> (shift + 8)) == pfx);
            if (cand) atomicAdd(&hp[(u >> shift) & 255u], 1u);
        }
        __syncthreads();
        unsigned int h = 0, s = 0;
        if (tid < 256) {
            #pragma unroll
            for (int w = 0; w < NW; ++w) { h += hist[w * 256 + tid]; hist[w * 256 + tid] = 0u; }
            s = h;  // suffix-inclusive scan within wave (bin order)
            for (int off = 1; off < 64; off <<= 1) {
                unsigned int v2 = __shfl_down(s, off, 64);
                if (lane + off < 64) s += v2;
            }
            if (lane == 0) wtot4[wid] = s;
        }
        __syncthreads();
        if (tid < 256) {
            unsigned int add = 0;
            #pragma unroll
            for (int w2 = 0; w2 < 4; ++w2) if (w2 > wid) add += wtot4[w2];
            unsigned int incl = s + add;       // # values in bins >= tid
            unsigned int excl = incl - h;      // # values in bins >  tid
            if (excl < krem && krem <= incl) { // exactly one thread
                sprefix = (pfx << 8) | (unsigned int)tid;
                sKrem   = krem - excl;
            }
        }
        __syncthreads();
    }
    const unsigned int T = sprefix;

    // ---- tie bookkeeping (stable: first (TOPK-G) equals in index order) ----
    unsigned int gt = 0, eq = 0;
    #pragma unroll
    for (int j = 0; j < 4; ++j) {
        gt += (cv[j] > T) ? 1u : 0u;
        eq += (cv[j] == T) ? 1u : 0u;
    }
    {
        unsigned int g = gt;
        for (int o = 32; o > 0; o >>= 1) g += __shfl_down(g, o, 64);
        if (lane == 0) atomicAdd(&sG, g);
    }
    unsigned int p = eq;
    for (int off = 1; off < 64; off <<= 1) {
        unsigned int v2 = __shfl_up(p, off, 64);
        if (lane >= off) p += v2;
    }
    if (lane == 63) weq[wid] = p;
    __syncthreads();
    unsigned int base = p - eq;
    #pragma unroll
    for (int w = 0; w < NW; ++w) if (w < wid) base += weq[w];
    const unsigned int needEq = TOPK - sG;

    // ---- emit masked x ----
    {
        unsigned int r = 0;
        float4 o;
        o.x = ((cv[0] > T) || ((cv[0] == T) && (base + r < needEq))) ? xv.x : 0.0f; r += (cv[0] == T);
        o.y = ((cv[1] > T) || ((cv[1] == T) && (base + r < needEq))) ? xv.y : 0.0f; r += (cv[1] == T);
        o.z = ((cv[2] > T) || ((cv[2] == T) && (base + r < needEq))) ? xv.z : 0.0f; r += (cv[2] == T);
        o.w = ((cv[3] > T) || ((cv[3] == T) && (base + r < needEq))) ? xv.w : 0.0f;
        reinterpret_cast<float4*>(xm)[tid] = o;
    }
}

// ---------------------------------------------------------------------------
// Kernel B: dense masked matvec, SEQUENTIAL per-block span.
// 256 blocks x 1024 threads. One row = one block-wide coalesced 16 KB load;
// block b sweeps rows 43b..43b+42 in order -> contiguous 688 KB stream.
// xm slice = 1 f4 register per thread. Per row: dot4 + wave reduce -> LDS
// partials; epilogue sums 16 wave-partials per row.
// ---------------------------------------------------------------------------
__global__ __launch_bounds__(NT) void matvec_kernel(
    const float* __restrict__ W,
    const float* __restrict__ xm,
    const float* __restrict__ bias,
    float* __restrict__ out)
{
    const int tid  = threadIdx.x;
    const int lane = tid & 63;
    const int wid  = tid >> 6;
    const int rbase = blockIdx.x * ROWS_PB;

    __shared__ float spart[ROWS_PB][NW + 1];   // +1 pad: conflict-free epilogue

    const f4 xv = ((const f4*)xm)[tid];        // this thread's fixed xm slice
    const f4* wp = (const f4*)(W + (size_t)rbase * IN_F);

    int r = 0;
    #pragma unroll 2
    for (; r + 4 <= ROWS_PB; r += 4) {         // 10 groups of 4 rows
        f4 wa = wp[(size_t)(r + 0) * 1024 + tid];
        f4 wb = wp[(size_t)(r + 1) * 1024 + tid];
        f4 wc = wp[(size_t)(r + 2) * 1024 + tid];
        f4 wd = wp[(size_t)(r + 3) * 1024 + tid];
        float pa = dotf4(wa, xv);
        float pb = dotf4(wb, xv);
        float pc = dotf4(wc, xv);
        float pd = dotf4(wd, xv);
        #pragma unroll
        for (int o = 32; o > 0; o >>= 1) {     // 4 independent reduce chains
            pa += __shfl_down(pa, o, 64);
            pb += __shfl_down(pb, o, 64);
            pc += __shfl_down(pc, o, 64);
            pd += __shfl_down(pd, o, 64);
        }
        if (lane == 0) {
            spart[r + 0][wid] = pa;
            spart[r + 1][wid] = pb;
            spart[r + 2][wid] = pc;
            spart[r + 3][wid] = pd;
        }
    }
    for (; r < ROWS_PB; ++r) {                 // 3 tail rows
        f4 w = wp[(size_t)r * 1024 + tid];
        float p = wredsum(dotf4(w, xv));
        if (lane == 0) spart[r][wid] = p;
    }
    __syncthreads();

    if (tid < ROWS_PB) {
        float s = 0.0f;
        #pragma unroll
        for (int w = 0; w < NW; ++w) s += spart[tid][w];
        const int row = rbase + tid;
        out[row] = s + bias[row];
    }
}

extern "C" void kernel_launch(void* const* d_in, const int* in_sizes, int n_in,
                              void* d_out, int out_size, void* d_ws, size_t ws_size,
                              hipStream_t stream) {
    const float* x       = (const float*)d_in[0];  // [1,1,4096]
    const float* weight  = (const float*)d_in[1];  // [11008,4096]
    const float* bias    = (const float*)d_in[2];  // [11008]
    const float* centers = (const float*)d_in[3];  // [16,4096]
    float* out = (float*)d_out;                    // [11008]
    float* xm  = (float*)d_ws;                     // 4096 floats scratch

    select_mask_kernel<<<1, NT, 0, stream>>>(x, centers, xm);
    matvec_kernel<<<256, NT, 0, stream>>>(weight, xm, bias, out);
}